// Round 13
// baseline (798.806 us; speedup 1.0000x reference)
//
#include <hip/hip_runtime.h>

#define NSTEP 16

typedef __attribute__((ext_vector_type(8))) short s16x8;
typedef __attribute__((ext_vector_type(4))) float f32x4;
typedef __attribute__((ext_vector_type(2))) float f32x2;

__device__ __forceinline__ float bf2f(unsigned short u){
  union { unsigned int i; float f; } v; v.i = ((unsigned int)u) << 16; return v.f;
}
__device__ __forceinline__ unsigned short f2bf(float f){
  union { float f; unsigned int i; } v; v.f = f;
  unsigned int r = v.i + 0x7fffu + ((v.i >> 16) & 1u);
  return (unsigned short)(r >> 16);
}
__device__ __forceinline__ float fast_rcp(float x){ return __builtin_amdgcn_rcpf(x); }
__device__ __forceinline__ float fast_tanh(float x){
  float e = __expf(2.0f * x);
  return 1.0f - 2.0f * fast_rcp(e + 1.0f);
}
__device__ __forceinline__ float fast_sigmoid(float x){
  return fast_rcp(1.0f + __expf(-x));
}
__device__ __forceinline__ void gload16(const void* g, void* l){
  __builtin_amdgcn_global_load_lds((const __attribute__((address_space(1))) void*)g,
                                   (__attribute__((address_space(3))) void*)l, 16, 0, 0);
}
__device__ __forceinline__ float wave_sum(float v){
#pragma unroll
  for (int off = 32; off; off >>= 1) v += __shfl_xor(v, off, 64);
  return v;
}
__device__ __forceinline__ void fp8x8_dec(uint2 w, float* u){
  f32x2 d0 = __builtin_amdgcn_cvt_pk_f32_fp8(w.x, false);
  f32x2 d1 = __builtin_amdgcn_cvt_pk_f32_fp8(w.x, true);
  f32x2 d2 = __builtin_amdgcn_cvt_pk_f32_fp8(w.y, false);
  f32x2 d3 = __builtin_amdgcn_cvt_pk_f32_fp8(w.y, true);
  u[0] = d0[0]; u[1] = d0[1]; u[2] = d1[0]; u[3] = d1[1];
  u[4] = d2[0]; u[5] = d2[1]; u[6] = d3[0]; u[7] = d3[1];
}
__device__ __forceinline__ s16x8 f32x8_to_bf8(float4 a, float4 b){
  s16x8 t8;
  t8[0] = (short)f2bf(a.x); t8[1] = (short)f2bf(a.y);
  t8[2] = (short)f2bf(a.z); t8[3] = (short)f2bf(a.w);
  t8[4] = (short)f2bf(b.x); t8[5] = (short)f2bf(b.y);
  t8[6] = (short)f2bf(b.z); t8[7] = (short)f2bf(b.w);
  return t8;
}
__device__ __forceinline__ uint2 f32x8_to_fp8(float4 a, float4 b){
  unsigned int lo, hi;
  lo = __builtin_amdgcn_cvt_pk_fp8_f32(a.x, a.y, 0, false);
  lo = __builtin_amdgcn_cvt_pk_fp8_f32(a.z, a.w, lo, true);
  hi = __builtin_amdgcn_cvt_pk_fp8_f32(b.x, b.y, 0, false);
  hi = __builtin_amdgcn_cvt_pk_fp8_f32(b.z, b.w, hi, true);
  uint2 w; w.x = lo; w.y = hi;
  return w;
}
__device__ __forceinline__ unsigned char f2fp8(float f){
  return (unsigned char)(__builtin_amdgcn_cvt_pk_fp8_f32(f, f, 0, false) & 0xff);
}

// ===== uxc_k: fused {x f32 -> bf16 A-staging} U-GEMM + x8 emission =====
// 128x128 tile, BK=64, grid (4, 512). A read from x (f32) once (simple staging);
// x8 store distributed: block (mt, nt) writes rows of mt for kt with kt>>7==nt.
struct GemmLDS { unsigned short A[128 * 64]; unsigned short B[128 * 64]; };  // 32 KB

__global__ __launch_bounds__(512) void uxc_k(
    const float* __restrict__ x, const unsigned short* __restrict__ Bt,
    unsigned char* __restrict__ U8, unsigned char* __restrict__ x8){
  __shared__ GemmLDS lds;
  const int tid = threadIdx.x;
  const int lane = tid & 63, wid = tid >> 6;
  const int wr = wid >> 2, wc = wid & 3;       // 2 x 4 waves, wave tile 64x32
  const int mt = blockIdx.y, nt = blockIdx.x;
  f32x4 acc[4][2];
#pragma unroll
  for (int m = 0; m < 4; ++m)
#pragma unroll
    for (int n = 0; n < 2; ++n) acc[m][n] = (f32x4)0.0f;

  for (int kt = 0; kt < 512; kt += 64){
    __syncthreads();
    {
      bool emit = (kt >> 7) == nt;
#pragma unroll
      for (int i = 0; i < 2; ++i){
        int s = i * 512 + tid;
        int row = s >> 3, c8 = s & 7;
        int sc = c8 ^ (row & 7);
        size_t goff = (size_t)(mt * 128 + row) * 512 + kt + sc * 8;
        const float* ap = x + goff;
        float4 a0 = *(const float4*)ap, a1 = *(const float4*)(ap + 4);
        *(s16x8*)&lds.A[s * 8] = f32x8_to_bf8(a0, a1);
        if (emit) *(uint2*)(x8 + goff) = f32x8_to_fp8(a0, a1);
      }
#pragma unroll
      for (int p = 0; p < 2; ++p){
        int s = p * 512 + tid;
        int br = s >> 3, bkc = (s & 7) ^ (br & 7);
        gload16(Bt + (size_t)(nt * 128 + br) * 512 + kt + bkc * 8, &lds.B[s * 8]);
      }
    }
    __syncthreads();
#pragma unroll
    for (int ks = 0; ks < 2; ++ks){
      int kc_l = (lane >> 4) + ks * 4;
      s16x8 av[4], bv[2];
#pragma unroll
      for (int m = 0; m < 4; ++m){
        int r = wr * 64 + m * 16 + (lane & 15);
        av[m] = *(const s16x8*)&lds.A[r * 64 + ((kc_l ^ (r & 7)) << 3)];
      }
#pragma unroll
      for (int n = 0; n < 2; ++n){
        int c = wc * 32 + n * 16 + (lane & 15);
        bv[n] = *(const s16x8*)&lds.B[c * 64 + ((kc_l ^ (c & 7)) << 3)];
      }
#pragma unroll
      for (int m = 0; m < 4; ++m)
#pragma unroll
        for (int n = 0; n < 2; ++n)
          acc[m][n] = __builtin_amdgcn_mfma_f32_16x16x32_bf16(av[m], bv[n], acc[m][n], 0, 0, 0);
    }
  }
#pragma unroll
  for (int m = 0; m < 4; ++m)
#pragma unroll
    for (int n = 0; n < 2; ++n){
      int r_base = mt * 128 + wr * 64 + m * 16 + ((lane >> 4) << 2);
      int col = nt * 128 + wc * 32 + n * 16 + (lane & 15);
#pragma unroll
      for (int q = 0; q < 4; ++q)
        U8[(size_t)(r_base + q) * 512 + col] = f2fp8(acc[m][n][q]);
    }
}

// ================= fast small GEMM: 64x64 tile, BK=256, 2 rounds =================
// EPI: 1 = s0 (tanh -> s_hist0 + s_bf; A from f32); 2 = pre1 (+bias, stride 2048);
//      4 = state update
struct FLDS { unsigned short A[64 * 256]; unsigned short B[64 * 256]; };  // 64 KB

template<int EPI, bool AF32>
__device__ __forceinline__ void fgemm_body(int mt, int nt,
    const unsigned short* __restrict__ A, const float* __restrict__ Af,
    const unsigned short* __restrict__ Bt,
    unsigned short* __restrict__ ob0, float* __restrict__ o0,
    const float* __restrict__ e0, const float* __restrict__ e1,
    const float* __restrict__ e2, FLDS& lds){
  const int tid = threadIdx.x;
  const int lane = tid & 63, wid = tid >> 6;
  const int wr = wid >> 1, wc = wid & 1;
  f32x4 acc[2];
  acc[0] = (f32x4)0.0f; acc[1] = (f32x4)0.0f;

  for (int kt = 0; kt < 512; kt += 256){
    if (kt) __syncthreads();
#pragma unroll
    for (int i = 0; i < 4; ++i){
      int s = i * 512 + tid;
      int row = s >> 5, c = s & 31;
      int sc = (c & 24) | ((c & 7) ^ (row & 7));
      if constexpr (AF32){
        const float* ap = Af + (size_t)(mt * 64 + row) * 512 + kt + sc * 8;
        float4 a0 = *(const float4*)ap, a1 = *(const float4*)(ap + 4);
        *(s16x8*)&lds.A[s * 8] = f32x8_to_bf8(a0, a1);
      } else {
        gload16(A + (size_t)(mt * 64 + row) * 512 + kt + sc * 8, &lds.A[s * 8]);
      }
      gload16(Bt + (size_t)(nt * 64 + row) * 512 + kt + sc * 8, &lds.B[s * 8]);
    }
    __syncthreads();
#pragma unroll
    for (int kk = 0; kk < 8; ++kk){
      int kch = kk * 4 + (lane >> 4);
      int ar = wr * 16 + (lane & 15);
      int asw = (kch & 24) | ((kch & 7) ^ (ar & 7));
      s16x8 av = *(const s16x8*)&lds.A[ar * 256 + asw * 8];
#pragma unroll
      for (int n = 0; n < 2; ++n){
        int br = wc * 32 + n * 16 + (lane & 15);
        int bsw = (kch & 24) | ((kch & 7) ^ (br & 7));
        s16x8 bv = *(const s16x8*)&lds.B[br * 256 + bsw * 8];
        acc[n] = __builtin_amdgcn_mfma_f32_16x16x32_bf16(av, bv, acc[n], 0, 0, 0);
      }
    }
  }

#pragma unroll
  for (int n = 0; n < 2; ++n){
    int r_base = mt * 64 + wr * 16 + ((lane >> 4) << 2);
    int col = nt * 64 + wc * 32 + n * 16 + (lane & 15);
#pragma unroll
    for (int q = 0; q < 4; ++q){
      float v = acc[n][q];
      size_t r_ = (size_t)(r_base + q);
      if constexpr (EPI == 1){
        float t = fast_tanh(v);
        o0[r_ * 512 + col] = t;
        ob0[r_ * 512 + col] = f2bf(t);
      } else if constexpr (EPI == 2){
        o0[r_ * 2048 + col] = v + e0[col];        // + bias_full
      } else if constexpr (EPI == 4){
        float v2 = v + e0[r_ * 512 + col];        // + cu0
        float sh = fast_tanh(v2);
        float z  = e1[r_ * 512 + col];            // z
        float so = e2[r_ * 512 + col];            // s_prev
        float sn = (1.0f - z) * so + z * sh;
        o0[r_ * 512 + col] = sn;                  // s_hist[step]
        ob0[r_ * 512 + col] = f2bf(sn);
      }
    }
  }
}

template<int EPI, bool AF32>
__global__ __launch_bounds__(512) void fgemm_k(
    const unsigned short* __restrict__ A, const float* __restrict__ Af,
    const unsigned short* __restrict__ Bt,
    unsigned short* __restrict__ ob0, float* __restrict__ o0,
    const float* __restrict__ e0, const float* __restrict__ e1,
    const float* __restrict__ e2){
  __shared__ FLDS lds;
  fgemm_body<EPI, AF32>(blockIdx.y, blockIdx.x, A, Af, Bt, ob0, o0, e0, e1, e2, lds);
}

// ec_k: grid (chunk=2, b=128), 512 thr (8 waves x 32 t each)   [R7-exact]
__global__ __launch_bounds__(512) void ec_k(const unsigned char* __restrict__ U8,
    const unsigned char* __restrict__ x8, const float* __restrict__ pre1,
    const float* __restrict__ va, float* __restrict__ cpart, float* __restrict__ psum){
  __shared__ float cred[8][512];
  __shared__ float pred[8];
  int chunk = blockIdx.x, b = blockIdx.y;
  int tid = threadIdx.x, lane = tid & 63, wid = tid >> 6;
  const float* pp = pre1 + (size_t)b * 2048 + lane * 8;
  float4 p0 = *(const float4*)pp, p1 = *(const float4*)(pp + 4);
  const float* vp = va + lane * 8;
  float4 v0 = *(const float4*)vp, v1 = *(const float4*)(vp + 4);
  float sv[8] = {p0.x, p0.y, p0.z, p0.w, p1.x, p1.y, p1.z, p1.w};
  float vv[8] = {v0.x, v0.y, v0.z, v0.w, v1.x, v1.y, v1.z, v1.w};
  float acc[8] = {0, 0, 0, 0, 0, 0, 0, 0};
  float psum_l = 0.f;
  int t0 = chunk * 256 + wid * 32;
  for (int i = 0; i < 32; ++i){
    int t = t0 + i;
    uint2 w = *(const uint2*)(U8 + ((size_t)t * 128 + b) * 512 + lane * 8);
    float u[8];
    fp8x8_dec(w, u);
    float e = 0.f;
#pragma unroll
    for (int k = 0; k < 8; ++k)
      e += fast_tanh(u[k] + sv[k]) * vv[k];
    e = wave_sum(e);
    float p = __expf(e);
    psum_l += p;
    uint2 wx = *(const uint2*)(x8 + ((size_t)t * 128 + b) * 512 + lane * 8);
    float ux[8];
    fp8x8_dec(wx, ux);
#pragma unroll
    for (int k = 0; k < 8; ++k) acc[k] += p * ux[k];
  }
#pragma unroll
  for (int k = 0; k < 8; ++k) cred[wid][lane * 8 + k] = acc[k];
  if (lane == 0) pred[wid] = psum_l;
  __syncthreads();
  float cs = 0.f;
#pragma unroll
  for (int w = 0; w < 8; ++w) cs += cred[w][tid];
  cpart[((size_t)chunk * 128 + b) * 512 + tid] = cs;
  if (tid == 0){
    float s = 0.f;
#pragma unroll
    for (int w = 0; w < 8; ++w) s += pred[w];
    psum[chunk * 128 + b] = s;
  }
}

// gates_k: 64x64 tiles (grid 24 x 2), A = c (2 partials, normalized)   [R7-exact]
__global__ __launch_bounds__(512) void gates_k(
    const float* __restrict__ cpart, const float* __restrict__ psum,
    const unsigned short* __restrict__ P2w, const float* __restrict__ pre1,
    const float* __restrict__ s_prev,
    unsigned short* __restrict__ rsb, float* __restrict__ zbuf, float* __restrict__ cu0){
  __shared__ FLDS lds;
  __shared__ float rden_s[64];
  const int tid = threadIdx.x;
  const int lane = tid & 63, wid = tid >> 6;
  const int wr = wid >> 1, wc = wid & 1;
  const int nt = blockIdx.x, mt = blockIdx.y;
  if (tid < 64){
    float d = psum[mt * 64 + tid] + psum[128 + mt * 64 + tid];
    rden_s[tid] = fast_rcp(d);
  }
  f32x4 acc[2];
  acc[0] = (f32x4)0.0f; acc[1] = (f32x4)0.0f;

  for (int kt = 0; kt < 512; kt += 256){
    __syncthreads();
#pragma unroll
    for (int i = 0; i < 4; ++i){
      int s = i * 512 + tid;
      int row = s >> 5, c = s & 31;
      int sc = (c & 24) | ((c & 7) ^ (row & 7));
      int b = mt * 64 + row;
      const float* cp0 = cpart + (size_t)b * 512 + kt + sc * 8;
      const float* cp1 = cp0 + (size_t)128 * 512;
      float rd = rden_s[row];
      float4 a0 = *(const float4*)cp0, a1 = *(const float4*)(cp0 + 4);
      float4 b0 = *(const float4*)cp1, b1 = *(const float4*)(cp1 + 4);
      s16x8 t8;
      t8[0] = (short)f2bf((a0.x + b0.x) * rd); t8[1] = (short)f2bf((a0.y + b0.y) * rd);
      t8[2] = (short)f2bf((a0.z + b0.z) * rd); t8[3] = (short)f2bf((a0.w + b0.w) * rd);
      t8[4] = (short)f2bf((a1.x + b1.x) * rd); t8[5] = (short)f2bf((a1.y + b1.y) * rd);
      t8[6] = (short)f2bf((a1.z + b1.z) * rd); t8[7] = (short)f2bf((a1.w + b1.w) * rd);
      *(s16x8*)&lds.A[s * 8] = t8;
      gload16(P2w + (size_t)(nt * 64 + row) * 512 + kt + sc * 8, &lds.B[s * 8]);
    }
    __syncthreads();
#pragma unroll
    for (int kk = 0; kk < 8; ++kk){
      int kch = kk * 4 + (lane >> 4);
      int ar = wr * 16 + (lane & 15);
      int asw = (kch & 24) | ((kch & 7) ^ (ar & 7));
      s16x8 av = *(const s16x8*)&lds.A[ar * 256 + asw * 8];
#pragma unroll
      for (int n = 0; n < 2; ++n){
        int br = wc * 32 + n * 16 + (lane & 15);
        int bsw = (kch & 24) | ((kch & 7) ^ (br & 7));
        s16x8 bv = *(const s16x8*)&lds.B[br * 256 + bsw * 8];
        acc[n] = __builtin_amdgcn_mfma_f32_16x16x32_bf16(av, bv, acc[n], 0, 0, 0);
      }
    }
  }

#pragma unroll
  for (int n = 0; n < 2; ++n){
    int r_base = mt * 64 + wr * 16 + ((lane >> 4) << 2);
    int col = nt * 64 + wc * 32 + n * 16 + (lane & 15);
#pragma unroll
    for (int q = 0; q < 4; ++q){
      float v = acc[n][q];
      size_t r_ = (size_t)(r_base + q);
      float v2 = v + pre1[r_ * 2048 + 512 + col];
      if (col < 512){
        float rg = fast_sigmoid(v2);
        rsb[r_ * 512 + col] = f2bf(rg * s_prev[r_ * 512 + col]);
      } else if (col < 1024){
        zbuf[r_ * 512 + (col - 512)] = fast_sigmoid(v2);
      } else {
        cu0[r_ * 512 + (col - 1024)] = v2;
      }
    }
  }
}

// dout_k: all outputs from s_hist in one pass
__global__ __launch_bounds__(512) void dout_k(const float* __restrict__ s_hist,
    const float* __restrict__ fcwT, const float* __restrict__ fcb,
    float* __restrict__ dout){
  int lane = threadIdx.x & 63, wid = threadIdx.x >> 6;
  int w = blockIdx.x * 8 + wid;            // 0..2047
  int step = w >> 7, b = w & 127;
  const float* sp = s_hist + (size_t)w * 512 + lane * 8;
  float4 sa = *(const float4*)sp, sb = *(const float4*)(sp + 4);
#pragma unroll
  for (int o = 0; o < 12; ++o){
    const float* fp = fcwT + (size_t)o * 512 + lane * 8;
    float4 fa = *(const float4*)fp, fb = *(const float4*)(fp + 4);
    float sum = sa.x * fa.x + sa.y * fa.y + sa.z * fa.z + sa.w * fa.w +
                sb.x * fb.x + sb.y * fb.y + sb.z * fb.z + sb.w * fb.w;
    sum = wave_sum(sum);
    if (lane == 0)
      dout[(size_t)b * (NSTEP * 12) + step * 12 + o] = sum + fcb[o];
  }
}

// weight prep: 10 transposed-bf16 matrices (with out-folding), fcwT, bias_full
__global__ __launch_bounds__(512) void trans_k(
    const float* __restrict__ ua, const float* __restrict__ wsm,
    const float* __restrict__ u0, const float* __restrict__ wa,
    const float* __restrict__ urm, const float* __restrict__ uz,
    const float* __restrict__ cr, const float* __restrict__ cz,
    const float* __restrict__ c0, const float* __restrict__ wrm,
    const float* __restrict__ wzm, const float* __restrict__ w0m,
    const float* __restrict__ fcw, const float* __restrict__ fcb,
    unsigned short* __restrict__ Pua, unsigned short* __restrict__ Pws,
    unsigned short* __restrict__ P3w, unsigned short* __restrict__ P1w,
    unsigned short* __restrict__ P2w, float* __restrict__ fcwT,
    float* __restrict__ bias_full){
  __shared__ unsigned short tr[64][72];
  int bid = blockIdx.x, tid = threadIdx.x;
  if (bid < 640){
    int mi = bid >> 6, tile = bid & 63;
    int trr = tile >> 3, tcc = tile & 7;
    const float* src = nullptr; const float* W = nullptr; unsigned short* dst;
    switch (mi){
      case 0: src = ua;  dst = Pua;               break;
      case 1: src = wsm; dst = Pws;               break;
      case 2: src = u0;  dst = P3w;               break;
      case 3: src = wa;  dst = P1w;               break;
      case 4: src = urm; dst = P1w + 512 * 512;  W = wrm; break;
      case 5: src = uz;  dst = P1w + 1024 * 512; W = wzm; break;
      case 6: src = nullptr; dst = P1w + 1536 * 512; W = w0m; break;
      case 7: src = cr;  dst = P2w;               break;
      case 8: src = cz;  dst = P2w + 512 * 512;   break;
      default:src = c0;  dst = P2w + 1024 * 512;  break;
    }
    int r = tid >> 3, c8 = (tid & 7) * 8;
    int h = trr * 64 + r;
    float vals[8];
    if (src){
      const float* sp = src + (size_t)h * 512 + tcc * 64 + c8;
      float4 a = *(const float4*)sp, b = *(const float4*)(sp + 4);
      vals[0] = a.x; vals[1] = a.y; vals[2] = a.z; vals[3] = a.w;
      vals[4] = b.x; vals[5] = b.y; vals[6] = b.z; vals[7] = b.w;
    } else {
#pragma unroll
      for (int k = 0; k < 8; ++k) vals[k] = 0.f;
    }
    if (W){
      float fr[12];
#pragma unroll
      for (int o = 0; o < 12; ++o) fr[o] = fcw[h * 12 + o];
#pragma unroll
      for (int jj = 0; jj < 8; ++jj){
        int j = tcc * 64 + c8 + jj;
        float cj = 0.f;
#pragma unroll
        for (int o = 0; o < 12; ++o) cj += fr[o] * W[o * 512 + j];
        vals[jj] += cj;
      }
    }
    unsigned short* lp = &tr[r][c8];
#pragma unroll
    for (int k = 0; k < 8; ++k) lp[k] = f2bf(vals[k]);
    __syncthreads();
    s16x8 o8v;
#pragma unroll
    for (int k = 0; k < 8; ++k) o8v[k] = (short)tr[c8 + k][r];
    *(s16x8*)(dst + (size_t)(tcc * 64 + r) * 512 + trr * 64 + c8) = o8v;
  } else if (bid < 652){
    int gidx = (bid - 640) * 512 + tid;   // 0..6143
    int h = gidx / 12, o = gidx - h * 12;
    fcwT[(size_t)o * 512 + h] = fcw[h * 12 + o];
  } else {
#pragma unroll
    for (int p = 0; p < 4; ++p){
      int col = p * 512 + tid;
      float v = 0.f;
      if (p > 0){
        const float* W = (p == 1) ? wrm : (p == 2) ? wzm : w0m;
#pragma unroll
        for (int o = 0; o < 12; ++o) v += fcb[o] * W[o * 512 + tid];
      }
      bias_full[col] = v;
    }
  }
}

// ---------------- host launch ----------------
extern "C" void kernel_launch(void* const* d_in, const int* in_sizes, int n_in,
                              void* d_out, int out_size, void* d_ws, size_t ws_size,
                              hipStream_t stream){
  const float* x   = (const float*)d_in[0];
  const float* w0  = (const float*)d_in[1];
  const float* wz  = (const float*)d_in[2];
  const float* wrm = (const float*)d_in[3];
  const float* wsm = (const float*)d_in[4];
  const float* wa  = (const float*)d_in[5];
  const float* ua  = (const float*)d_in[6];
  const float* va  = (const float*)d_in[7];
  const float* u0  = (const float*)d_in[8];
  const float* uz  = (const float*)d_in[9];
  const float* urm = (const float*)d_in[10];
  const float* c0  = (const float*)d_in[11];
  const float* cz  = (const float*)d_in[12];
  const float* cr  = (const float*)d_in[13];
  const float* fcw = (const float*)d_in[14];
  const float* fcb = (const float*)d_in[15];
  float* dout = (float*)d_out;

  char* base = (char*)d_ws;
  size_t off = 0;
  auto alloc = [&](size_t bytes) -> char* {
    char* p = base + off; off += (bytes + 255) & ~(size_t)255; return p;
  };
  unsigned char*  x8   = (unsigned char*) alloc((size_t)512 * 128 * 512);
  unsigned char*  U8   = (unsigned char*) alloc((size_t)512 * 128 * 512);
  unsigned short* Pua  = (unsigned short*)alloc(512 * 512 * 2);
  unsigned short* Pws  = (unsigned short*)alloc(512 * 512 * 2);
  unsigned short* P3w  = (unsigned short*)alloc(512 * 512 * 2);
  unsigned short* P1w  = (unsigned short*)alloc((size_t)2048 * 512 * 2);
  unsigned short* P2w  = (unsigned short*)alloc((size_t)1536 * 512 * 2);
  float* fcwT          = (float*)alloc(12 * 512 * 4);
  float* bias_full     = (float*)alloc(2048 * 4);
  float* pre1          = (float*)alloc((size_t)128 * 2048 * 4);
  float* cpart         = (float*)alloc((size_t)2 * 128 * 512 * 4);
  float* psum          = (float*)alloc(2 * 128 * 4);
  unsigned short* rsb  = (unsigned short*)alloc((size_t)128 * 512 * 2);
  float* zbuf          = (float*)alloc((size_t)128 * 512 * 4);
  float* cu0           = (float*)alloc((size_t)128 * 512 * 4);
  float* s_hist        = (float*)alloc((size_t)NSTEP * 128 * 512 * 4);
  unsigned short* s_bf = (unsigned short*)alloc((size_t)128 * 512 * 2);
  (void)ws_size; (void)in_sizes; (void)n_in; (void)out_size;

  // setup
  trans_k<<<653, 512, 0, stream>>>(ua, wsm, u0, wa, urm, uz, cr, cz, c0,
                                   wrm, wz, w0, fcw, fcb,
                                   Pua, Pws, P3w, P1w, P2w, fcwT, bias_full);
  // U = x @ ua (fp8 out) + x8 emission, A staged from f32 x (128x128 tile)
  uxc_k<<<dim3(4, 512), 512, 0, stream>>>(x, Pua, U8, x8);
  // s0 = tanh(x0 @ ws) -> s_hist[0] + s_bf  (A from f32 x rows 0..127)
  fgemm_k<1, true><<<dim3(8, 2), 512, 0, stream>>>(nullptr, x, Pws, s_bf, s_hist,
                                                   nullptr, nullptr, nullptr);

  for (int step = 1; step < NSTEP; ++step){
    const float* s_prev = s_hist + (size_t)(step - 1) * 128 * 512;
    float* s_cur = s_hist + (size_t)step * 128 * 512;
    // pre1 = s @ [wa|ur'|uz'|uw0] + bias
    fgemm_k<2, false><<<dim3(32, 2), 512, 0, stream>>>(s_bf, nullptr, P1w,
                                                       nullptr, pre1,
                                                       bias_full, nullptr, nullptr);
    ec_k<<<dim3(2, 128), 512, 0, stream>>>(U8, x8, pre1, va, cpart, psum);
    gates_k<<<dim3(24, 2), 512, 0, stream>>>(cpart, psum, P2w, pre1, s_prev,
                                             rsb, zbuf, cu0);
    fgemm_k<4, false><<<dim3(8, 2), 512, 0, stream>>>(rsb, nullptr, P3w,
                                                      s_bf, s_cur,
                                                      cu0, zbuf, s_prev);
  }
  dout_k<<<256, 512, 0, stream>>>(s_hist, fcwT, fcb, dout);
}

// Round 14
// 784.203 us; speedup vs baseline: 1.0186x; 1.0186x over previous
//
#include <hip/hip_runtime.h>

#define NSTEP 16

typedef __attribute__((ext_vector_type(8))) short s16x8;
typedef __attribute__((ext_vector_type(4))) float f32x4;
typedef __attribute__((ext_vector_type(2))) float f32x2;

__device__ __forceinline__ float bf2f(unsigned short u){
  union { unsigned int i; float f; } v; v.i = ((unsigned int)u) << 16; return v.f;
}
__device__ __forceinline__ unsigned short f2bf(float f){
  union { float f; unsigned int i; } v; v.f = f;
  unsigned int r = v.i + 0x7fffu + ((v.i >> 16) & 1u);
  return (unsigned short)(r >> 16);
}
__device__ __forceinline__ float fast_rcp(float x){ return __builtin_amdgcn_rcpf(x); }
__device__ __forceinline__ float fast_tanh(float x){
  float e = __expf(2.0f * x);
  return 1.0f - 2.0f * fast_rcp(e + 1.0f);
}
__device__ __forceinline__ float fast_sigmoid(float x){
  return fast_rcp(1.0f + __expf(-x));
}
__device__ __forceinline__ void gload16(const void* g, void* l){
  __builtin_amdgcn_global_load_lds((const __attribute__((address_space(1))) void*)g,
                                   (__attribute__((address_space(3))) void*)l, 16, 0, 0);
}
__device__ __forceinline__ float wave_sum(float v){
#pragma unroll
  for (int off = 32; off; off >>= 1) v += __shfl_xor(v, off, 64);
  return v;
}
__device__ __forceinline__ void fp8x8_dec(uint2 w, float* u){
  f32x2 d0 = __builtin_amdgcn_cvt_pk_f32_fp8(w.x, false);
  f32x2 d1 = __builtin_amdgcn_cvt_pk_f32_fp8(w.x, true);
  f32x2 d2 = __builtin_amdgcn_cvt_pk_f32_fp8(w.y, false);
  f32x2 d3 = __builtin_amdgcn_cvt_pk_f32_fp8(w.y, true);
  u[0] = d0[0]; u[1] = d0[1]; u[2] = d1[0]; u[3] = d1[1];
  u[4] = d2[0]; u[5] = d2[1]; u[6] = d3[0]; u[7] = d3[1];
}
__device__ __forceinline__ s16x8 f32x8_to_bf8(float4 a, float4 b){
  s16x8 t8;
  t8[0] = (short)f2bf(a.x); t8[1] = (short)f2bf(a.y);
  t8[2] = (short)f2bf(a.z); t8[3] = (short)f2bf(a.w);
  t8[4] = (short)f2bf(b.x); t8[5] = (short)f2bf(b.y);
  t8[6] = (short)f2bf(b.z); t8[7] = (short)f2bf(b.w);
  return t8;
}
__device__ __forceinline__ uint2 f32x8_to_fp8(float4 a, float4 b){
  unsigned int lo, hi;
  lo = __builtin_amdgcn_cvt_pk_fp8_f32(a.x, a.y, 0, false);
  lo = __builtin_amdgcn_cvt_pk_fp8_f32(a.z, a.w, lo, true);
  hi = __builtin_amdgcn_cvt_pk_fp8_f32(b.x, b.y, 0, false);
  hi = __builtin_amdgcn_cvt_pk_fp8_f32(b.z, b.w, hi, true);
  uint2 w; w.x = lo; w.y = hi;
  return w;
}
__device__ __forceinline__ unsigned char f2fp8(float f){
  return (unsigned char)(__builtin_amdgcn_cvt_pk_fp8_f32(f, f, 0, false) & 0xff);
}

// ===== castx_k: x f32 -> x8 (fp8), pure stream =====
__global__ __launch_bounds__(256) void castx_k(const float* __restrict__ x,
                                               unsigned char* __restrict__ x8){
  size_t idx = (size_t)blockIdx.x * 256 + threadIdx.x;
  const float* p = x + idx * 8;
  float4 a = *(const float4*)p, b = *(const float4*)(p + 4);
  *(uint2*)(x8 + idx * 8) = f32x8_to_fp8(a, b);
}

// ===== ugemm8_k: U8 = fp8( (x8 @ Pua8) * 0.125 ), fp8 MFMA =====
// 128x128 tile, BK=64, grid (4, 512). LDS 16 KB. Pua8 holds fp8(8*ua^T).
// Staging: 16B-granule XOR swizzle sc16 = j ^ (row&3) (pre-swizzled source,
// linear gload_lds dest); read at 8B granule g -> g ^ ((row&3)<<1).
struct G8LDS { unsigned char A[128 * 64]; unsigned char B[128 * 64]; };

__global__ __launch_bounds__(512) void ugemm8_k(
    const unsigned char* __restrict__ x8, const unsigned char* __restrict__ Pua8,
    unsigned char* __restrict__ U8){
  __shared__ G8LDS lds;
  const int tid = threadIdx.x;
  const int lane = tid & 63, wid = tid >> 6;
  const int wr = wid >> 2, wc = wid & 3;     // 2 x 4 waves, wave tile 64x32
  const int mt = blockIdx.y, nt = blockIdx.x;
  f32x4 acc[4][2];
#pragma unroll
  for (int m = 0; m < 4; ++m)
#pragma unroll
    for (int n = 0; n < 2; ++n) acc[m][n] = (f32x4)0.0f;

  const int row = tid >> 2, j = tid & 3;
  const int sc16 = j ^ (row & 3);
  for (int kt = 0; kt < 512; kt += 64){
    __syncthreads();
    gload16(x8  + (size_t)(mt * 128 + row) * 512 + kt + sc16 * 16, &lds.A[tid * 16]);
    gload16(Pua8 + (size_t)(nt * 128 + row) * 512 + kt + sc16 * 16, &lds.B[tid * 16]);
    __syncthreads();
#pragma unroll
    for (int ks = 0; ks < 2; ++ks){
      int g = (lane >> 4) + ks * 4;
      long av[4], bv[2];
#pragma unroll
      for (int m = 0; m < 4; ++m){
        int r = wr * 64 + m * 16 + (lane & 15);
        av[m] = *(const long*)&lds.A[r * 64 + ((g ^ ((r & 3) << 1)) << 3)];
      }
#pragma unroll
      for (int n = 0; n < 2; ++n){
        int c = wc * 32 + n * 16 + (lane & 15);
        bv[n] = *(const long*)&lds.B[c * 64 + ((g ^ ((c & 3) << 1)) << 3)];
      }
#pragma unroll
      for (int m = 0; m < 4; ++m)
#pragma unroll
        for (int n = 0; n < 2; ++n)
          acc[m][n] = __builtin_amdgcn_mfma_f32_16x16x32_fp8_fp8(av[m], bv[n], acc[m][n], 0, 0, 0);
    }
  }
#pragma unroll
  for (int m = 0; m < 4; ++m)
#pragma unroll
    for (int n = 0; n < 2; ++n){
      int r_base = mt * 128 + wr * 64 + m * 16 + ((lane >> 4) << 2);
      int col = nt * 128 + wc * 32 + n * 16 + (lane & 15);
#pragma unroll
      for (int q = 0; q < 4; ++q)
        U8[(size_t)(r_base + q) * 512 + col] = f2fp8(acc[m][n][q] * 0.125f);
    }
}

// ================= fast small GEMM: 64x64 tile, BK=256, 2 rounds =================
// EPI: 1 = s0 (tanh -> s_hist0 + s_bf; A from f32); 2 = pre1 (+bias, stride 2048);
//      4 = state update
struct FLDS { unsigned short A[64 * 256]; unsigned short B[64 * 256]; };  // 64 KB

template<int EPI, bool AF32>
__device__ __forceinline__ void fgemm_body(int mt, int nt,
    const unsigned short* __restrict__ A, const float* __restrict__ Af,
    const unsigned short* __restrict__ Bt,
    unsigned short* __restrict__ ob0, float* __restrict__ o0,
    const float* __restrict__ e0, const float* __restrict__ e1,
    const float* __restrict__ e2, FLDS& lds){
  const int tid = threadIdx.x;
  const int lane = tid & 63, wid = tid >> 6;
  const int wr = wid >> 1, wc = wid & 1;
  f32x4 acc[2];
  acc[0] = (f32x4)0.0f; acc[1] = (f32x4)0.0f;

  for (int kt = 0; kt < 512; kt += 256){
    if (kt) __syncthreads();
#pragma unroll
    for (int i = 0; i < 4; ++i){
      int s = i * 512 + tid;
      int row = s >> 5, c = s & 31;
      int sc = (c & 24) | ((c & 7) ^ (row & 7));
      if constexpr (AF32){
        const float* ap = Af + (size_t)(mt * 64 + row) * 512 + kt + sc * 8;
        float4 a0 = *(const float4*)ap, a1 = *(const float4*)(ap + 4);
        *(s16x8*)&lds.A[s * 8] = f32x8_to_bf8(a0, a1);
      } else {
        gload16(A + (size_t)(mt * 64 + row) * 512 + kt + sc * 8, &lds.A[s * 8]);
      }
      gload16(Bt + (size_t)(nt * 64 + row) * 512 + kt + sc * 8, &lds.B[s * 8]);
    }
    __syncthreads();
#pragma unroll
    for (int kk = 0; kk < 8; ++kk){
      int kch = kk * 4 + (lane >> 4);
      int ar = wr * 16 + (lane & 15);
      int asw = (kch & 24) | ((kch & 7) ^ (ar & 7));
      s16x8 av = *(const s16x8*)&lds.A[ar * 256 + asw * 8];
#pragma unroll
      for (int n = 0; n < 2; ++n){
        int br = wc * 32 + n * 16 + (lane & 15);
        int bsw = (kch & 24) | ((kch & 7) ^ (br & 7));
        s16x8 bv = *(const s16x8*)&lds.B[br * 256 + bsw * 8];
        acc[n] = __builtin_amdgcn_mfma_f32_16x16x32_bf16(av, bv, acc[n], 0, 0, 0);
      }
    }
  }

#pragma unroll
  for (int n = 0; n < 2; ++n){
    int r_base = mt * 64 + wr * 16 + ((lane >> 4) << 2);
    int col = nt * 64 + wc * 32 + n * 16 + (lane & 15);
#pragma unroll
    for (int q = 0; q < 4; ++q){
      float v = acc[n][q];
      size_t r_ = (size_t)(r_base + q);
      if constexpr (EPI == 1){
        float t = fast_tanh(v);
        o0[r_ * 512 + col] = t;
        ob0[r_ * 512 + col] = f2bf(t);
      } else if constexpr (EPI == 2){
        o0[r_ * 2048 + col] = v + e0[col];        // + bias_full
      } else if constexpr (EPI == 4){
        float v2 = v + e0[r_ * 512 + col];        // + cu0
        float sh = fast_tanh(v2);
        float z  = e1[r_ * 512 + col];            // z
        float so = e2[r_ * 512 + col];            // s_prev
        float sn = (1.0f - z) * so + z * sh;
        o0[r_ * 512 + col] = sn;                  // s_hist[step]
        ob0[r_ * 512 + col] = f2bf(sn);
      }
    }
  }
}

template<int EPI, bool AF32>
__global__ __launch_bounds__(512) void fgemm_k(
    const unsigned short* __restrict__ A, const float* __restrict__ Af,
    const unsigned short* __restrict__ Bt,
    unsigned short* __restrict__ ob0, float* __restrict__ o0,
    const float* __restrict__ e0, const float* __restrict__ e1,
    const float* __restrict__ e2){
  __shared__ FLDS lds;
  fgemm_body<EPI, AF32>(blockIdx.y, blockIdx.x, A, Af, Bt, ob0, o0, e0, e1, e2, lds);
}

// ec_k: grid (chunk=2, b=128), 512 thr (8 waves x 32 t each)   [R7-exact]
__global__ __launch_bounds__(512) void ec_k(const unsigned char* __restrict__ U8,
    const unsigned char* __restrict__ x8, const float* __restrict__ pre1,
    const float* __restrict__ va, float* __restrict__ cpart, float* __restrict__ psum){
  __shared__ float cred[8][512];
  __shared__ float pred[8];
  int chunk = blockIdx.x, b = blockIdx.y;
  int tid = threadIdx.x, lane = tid & 63, wid = tid >> 6;
  const float* pp = pre1 + (size_t)b * 2048 + lane * 8;
  float4 p0 = *(const float4*)pp, p1 = *(const float4*)(pp + 4);
  const float* vp = va + lane * 8;
  float4 v0 = *(const float4*)vp, v1 = *(const float4*)(vp + 4);
  float sv[8] = {p0.x, p0.y, p0.z, p0.w, p1.x, p1.y, p1.z, p1.w};
  float vv[8] = {v0.x, v0.y, v0.z, v0.w, v1.x, v1.y, v1.z, v1.w};
  float acc[8] = {0, 0, 0, 0, 0, 0, 0, 0};
  float psum_l = 0.f;
  int t0 = chunk * 256 + wid * 32;
  for (int i = 0; i < 32; ++i){
    int t = t0 + i;
    uint2 w = *(const uint2*)(U8 + ((size_t)t * 128 + b) * 512 + lane * 8);
    float u[8];
    fp8x8_dec(w, u);
    float e = 0.f;
#pragma unroll
    for (int k = 0; k < 8; ++k)
      e += fast_tanh(u[k] + sv[k]) * vv[k];
    e = wave_sum(e);
    float p = __expf(e);
    psum_l += p;
    uint2 wx = *(const uint2*)(x8 + ((size_t)t * 128 + b) * 512 + lane * 8);
    float ux[8];
    fp8x8_dec(wx, ux);
#pragma unroll
    for (int k = 0; k < 8; ++k) acc[k] += p * ux[k];
  }
#pragma unroll
  for (int k = 0; k < 8; ++k) cred[wid][lane * 8 + k] = acc[k];
  if (lane == 0) pred[wid] = psum_l;
  __syncthreads();
  float cs = 0.f;
#pragma unroll
  for (int w = 0; w < 8; ++w) cs += cred[w][tid];
  cpart[((size_t)chunk * 128 + b) * 512 + tid] = cs;
  if (tid == 0){
    float s = 0.f;
#pragma unroll
    for (int w = 0; w < 8; ++w) s += pred[w];
    psum[chunk * 128 + b] = s;
  }
}

// gates_k: 64x64 tiles (grid 24 x 2), A = c (2 partials, normalized)   [R7-exact]
__global__ __launch_bounds__(512) void gates_k(
    const float* __restrict__ cpart, const float* __restrict__ psum,
    const unsigned short* __restrict__ P2w, const float* __restrict__ pre1,
    const float* __restrict__ s_prev,
    unsigned short* __restrict__ rsb, float* __restrict__ zbuf, float* __restrict__ cu0){
  __shared__ FLDS lds;
  __shared__ float rden_s[64];
  const int tid = threadIdx.x;
  const int lane = tid & 63, wid = tid >> 6;
  const int wr = wid >> 1, wc = wid & 1;
  const int nt = blockIdx.x, mt = blockIdx.y;
  if (tid < 64){
    float d = psum[mt * 64 + tid] + psum[128 + mt * 64 + tid];
    rden_s[tid] = fast_rcp(d);
  }
  f32x4 acc[2];
  acc[0] = (f32x4)0.0f; acc[1] = (f32x4)0.0f;

  for (int kt = 0; kt < 512; kt += 256){
    __syncthreads();
#pragma unroll
    for (int i = 0; i < 4; ++i){
      int s = i * 512 + tid;
      int row = s >> 5, c = s & 31;
      int sc = (c & 24) | ((c & 7) ^ (row & 7));
      int b = mt * 64 + row;
      const float* cp0 = cpart + (size_t)b * 512 + kt + sc * 8;
      const float* cp1 = cp0 + (size_t)128 * 512;
      float rd = rden_s[row];
      float4 a0 = *(const float4*)cp0, a1 = *(const float4*)(cp0 + 4);
      float4 b0 = *(const float4*)cp1, b1 = *(const float4*)(cp1 + 4);
      s16x8 t8;
      t8[0] = (short)f2bf((a0.x + b0.x) * rd); t8[1] = (short)f2bf((a0.y + b0.y) * rd);
      t8[2] = (short)f2bf((a0.z + b0.z) * rd); t8[3] = (short)f2bf((a0.w + b0.w) * rd);
      t8[4] = (short)f2bf((a1.x + b1.x) * rd); t8[5] = (short)f2bf((a1.y + b1.y) * rd);
      t8[6] = (short)f2bf((a1.z + b1.z) * rd); t8[7] = (short)f2bf((a1.w + b1.w) * rd);
      *(s16x8*)&lds.A[s * 8] = t8;
      gload16(P2w + (size_t)(nt * 64 + row) * 512 + kt + sc * 8, &lds.B[s * 8]);
    }
    __syncthreads();
#pragma unroll
    for (int kk = 0; kk < 8; ++kk){
      int kch = kk * 4 + (lane >> 4);
      int ar = wr * 16 + (lane & 15);
      int asw = (kch & 24) | ((kch & 7) ^ (ar & 7));
      s16x8 av = *(const s16x8*)&lds.A[ar * 256 + asw * 8];
#pragma unroll
      for (int n = 0; n < 2; ++n){
        int br = wc * 32 + n * 16 + (lane & 15);
        int bsw = (kch & 24) | ((kch & 7) ^ (br & 7));
        s16x8 bv = *(const s16x8*)&lds.B[br * 256 + bsw * 8];
        acc[n] = __builtin_amdgcn_mfma_f32_16x16x32_bf16(av, bv, acc[n], 0, 0, 0);
      }
    }
  }

#pragma unroll
  for (int n = 0; n < 2; ++n){
    int r_base = mt * 64 + wr * 16 + ((lane >> 4) << 2);
    int col = nt * 64 + wc * 32 + n * 16 + (lane & 15);
#pragma unroll
    for (int q = 0; q < 4; ++q){
      float v = acc[n][q];
      size_t r_ = (size_t)(r_base + q);
      float v2 = v + pre1[r_ * 2048 + 512 + col];
      if (col < 512){
        float rg = fast_sigmoid(v2);
        rsb[r_ * 512 + col] = f2bf(rg * s_prev[r_ * 512 + col]);
      } else if (col < 1024){
        zbuf[r_ * 512 + (col - 512)] = fast_sigmoid(v2);
      } else {
        cu0[r_ * 512 + (col - 1024)] = v2;
      }
    }
  }
}

// dout_k: all outputs from s_hist in one pass
__global__ __launch_bounds__(512) void dout_k(const float* __restrict__ s_hist,
    const float* __restrict__ fcwT, const float* __restrict__ fcb,
    float* __restrict__ dout){
  int lane = threadIdx.x & 63, wid = threadIdx.x >> 6;
  int w = blockIdx.x * 8 + wid;            // 0..2047
  int step = w >> 7, b = w & 127;
  const float* sp = s_hist + (size_t)w * 512 + lane * 8;
  float4 sa = *(const float4*)sp, sb = *(const float4*)(sp + 4);
#pragma unroll
  for (int o = 0; o < 12; ++o){
    const float* fp = fcwT + (size_t)o * 512 + lane * 8;
    float4 fa = *(const float4*)fp, fb = *(const float4*)(fp + 4);
    float sum = sa.x * fa.x + sa.y * fa.y + sa.z * fa.z + sa.w * fa.w +
                sb.x * fb.x + sb.y * fb.y + sb.z * fb.z + sb.w * fb.w;
    sum = wave_sum(sum);
    if (lane == 0)
      dout[(size_t)b * (NSTEP * 12) + step * 12 + o] = sum + fcb[o];
  }
}

// weight prep: transposed matrices (ua -> fp8x8 Pua8; rest bf16, with
// out-folding), fcwT, bias_full
__global__ __launch_bounds__(512) void trans_k(
    const float* __restrict__ ua, const float* __restrict__ wsm,
    const float* __restrict__ u0, const float* __restrict__ wa,
    const float* __restrict__ urm, const float* __restrict__ uz,
    const float* __restrict__ cr, const float* __restrict__ cz,
    const float* __restrict__ c0, const float* __restrict__ wrm,
    const float* __restrict__ wzm, const float* __restrict__ w0m,
    const float* __restrict__ fcw, const float* __restrict__ fcb,
    unsigned char* __restrict__ Pua8, unsigned short* __restrict__ Pws,
    unsigned short* __restrict__ P3w, unsigned short* __restrict__ P1w,
    unsigned short* __restrict__ P2w, float* __restrict__ fcwT,
    float* __restrict__ bias_full){
  __shared__ unsigned short tr[64][72];
  int bid = blockIdx.x, tid = threadIdx.x;
  if (bid < 640){
    int mi = bid >> 6, tile = bid & 63;
    int trr = tile >> 3, tcc = tile & 7;
    const float* src = nullptr; const float* W = nullptr; unsigned short* dst = nullptr;
    switch (mi){
      case 0: src = ua;  dst = nullptr;           break;   // -> Pua8 (fp8)
      case 1: src = wsm; dst = Pws;               break;
      case 2: src = u0;  dst = P3w;               break;
      case 3: src = wa;  dst = P1w;               break;
      case 4: src = urm; dst = P1w + 512 * 512;  W = wrm; break;
      case 5: src = uz;  dst = P1w + 1024 * 512; W = wzm; break;
      case 6: src = nullptr; dst = P1w + 1536 * 512; W = w0m; break;
      case 7: src = cr;  dst = P2w;               break;
      case 8: src = cz;  dst = P2w + 512 * 512;   break;
      default:src = c0;  dst = P2w + 1024 * 512;  break;
    }
    int r = tid >> 3, c8 = (tid & 7) * 8;
    int h = trr * 64 + r;
    float vals[8];
    if (src){
      const float* sp = src + (size_t)h * 512 + tcc * 64 + c8;
      float4 a = *(const float4*)sp, b = *(const float4*)(sp + 4);
      vals[0] = a.x; vals[1] = a.y; vals[2] = a.z; vals[3] = a.w;
      vals[4] = b.x; vals[5] = b.y; vals[6] = b.z; vals[7] = b.w;
    } else {
#pragma unroll
      for (int k = 0; k < 8; ++k) vals[k] = 0.f;
    }
    if (W){
      float fr[12];
#pragma unroll
      for (int o = 0; o < 12; ++o) fr[o] = fcw[h * 12 + o];
#pragma unroll
      for (int jj = 0; jj < 8; ++jj){
        int j = tcc * 64 + c8 + jj;
        float cj = 0.f;
#pragma unroll
        for (int o = 0; o < 12; ++o) cj += fr[o] * W[o * 512 + j];
        vals[jj] += cj;
      }
    }
    unsigned short* lp = &tr[r][c8];
#pragma unroll
    for (int k = 0; k < 8; ++k) lp[k] = f2bf(vals[k]);
    __syncthreads();
    if (mi == 0){
      // fp8(8 * ua^T) for the fp8 U-GEMM B-operand
      float v[8];
#pragma unroll
      for (int k = 0; k < 8; ++k) v[k] = bf2f(tr[c8 + k][r]) * 8.0f;
      float4 a; a.x = v[0]; a.y = v[1]; a.z = v[2]; a.w = v[3];
      float4 b; b.x = v[4]; b.y = v[5]; b.z = v[6]; b.w = v[7];
      *(uint2*)(Pua8 + (size_t)(tcc * 64 + r) * 512 + trr * 64 + c8) = f32x8_to_fp8(a, b);
    } else {
      s16x8 o8v;
#pragma unroll
      for (int k = 0; k < 8; ++k) o8v[k] = (short)tr[c8 + k][r];
      *(s16x8*)(dst + (size_t)(tcc * 64 + r) * 512 + trr * 64 + c8) = o8v;
    }
  } else if (bid < 652){
    int gidx = (bid - 640) * 512 + tid;   // 0..6143
    int h = gidx / 12, o = gidx - h * 12;
    fcwT[(size_t)o * 512 + h] = fcw[h * 12 + o];
  } else {
#pragma unroll
    for (int p = 0; p < 4; ++p){
      int col = p * 512 + tid;
      float v = 0.f;
      if (p > 0){
        const float* W = (p == 1) ? wrm : (p == 2) ? wzm : w0m;
#pragma unroll
        for (int o = 0; o < 12; ++o) v += fcb[o] * W[o * 512 + tid];
      }
      bias_full[col] = v;
    }
  }
}

// ---------------- host launch ----------------
extern "C" void kernel_launch(void* const* d_in, const int* in_sizes, int n_in,
                              void* d_out, int out_size, void* d_ws, size_t ws_size,
                              hipStream_t stream){
  const float* x   = (const float*)d_in[0];
  const float* w0  = (const float*)d_in[1];
  const float* wz  = (const float*)d_in[2];
  const float* wrm = (const float*)d_in[3];
  const float* wsm = (const float*)d_in[4];
  const float* wa  = (const float*)d_in[5];
  const float* ua  = (const float*)d_in[6];
  const float* va  = (const float*)d_in[7];
  const float* u0  = (const float*)d_in[8];
  const float* uz  = (const float*)d_in[9];
  const float* urm = (const float*)d_in[10];
  const float* c0  = (const float*)d_in[11];
  const float* cz  = (const float*)d_in[12];
  const float* cr  = (const float*)d_in[13];
  const float* fcw = (const float*)d_in[14];
  const float* fcb = (const float*)d_in[15];
  float* dout = (float*)d_out;

  char* base = (char*)d_ws;
  size_t off = 0;
  auto alloc = [&](size_t bytes) -> char* {
    char* p = base + off; off += (bytes + 255) & ~(size_t)255; return p;
  };
  unsigned char*  x8   = (unsigned char*) alloc((size_t)512 * 128 * 512);
  unsigned char*  U8   = (unsigned char*) alloc((size_t)512 * 128 * 512);
  unsigned char*  Pua8 = (unsigned char*) alloc(512 * 512);
  unsigned short* Pws  = (unsigned short*)alloc(512 * 512 * 2);
  unsigned short* P3w  = (unsigned short*)alloc(512 * 512 * 2);
  unsigned short* P1w  = (unsigned short*)alloc((size_t)2048 * 512 * 2);
  unsigned short* P2w  = (unsigned short*)alloc((size_t)1536 * 512 * 2);
  float* fcwT          = (float*)alloc(12 * 512 * 4);
  float* bias_full     = (float*)alloc(2048 * 4);
  float* pre1          = (float*)alloc((size_t)128 * 2048 * 4);
  float* cpart         = (float*)alloc((size_t)2 * 128 * 512 * 4);
  float* psum          = (float*)alloc(2 * 128 * 4);
  unsigned short* rsb  = (unsigned short*)alloc((size_t)128 * 512 * 2);
  float* zbuf          = (float*)alloc((size_t)128 * 512 * 4);
  float* cu0           = (float*)alloc((size_t)128 * 512 * 4);
  float* s_hist        = (float*)alloc((size_t)NSTEP * 128 * 512 * 4);
  unsigned short* s_bf = (unsigned short*)alloc((size_t)128 * 512 * 2);
  (void)ws_size; (void)in_sizes; (void)n_in; (void)out_size;

  // setup
  trans_k<<<653, 512, 0, stream>>>(ua, wsm, u0, wa, urm, uz, cr, cz, c0,
                                   wrm, wz, w0, fcw, fcb,
                                   Pua8, Pws, P3w, P1w, P2w, fcwT, bias_full);
  castx_k<<<16384, 256, 0, stream>>>(x, x8);
  // U8 = fp8( (x8 @ fp8(8*ua)) / 8 )
  ugemm8_k<<<dim3(4, 512), 512, 0, stream>>>(x8, Pua8, U8);
  // s0 = tanh(x0 @ ws) -> s_hist[0] + s_bf  (A from f32 x rows 0..127)
  fgemm_k<1, true><<<dim3(8, 2), 512, 0, stream>>>(nullptr, x, Pws, s_bf, s_hist,
                                                   nullptr, nullptr, nullptr);

  for (int step = 1; step < NSTEP; ++step){
    const float* s_prev = s_hist + (size_t)(step - 1) * 128 * 512;
    float* s_cur = s_hist + (size_t)step * 128 * 512;
    // pre1 = s @ [wa|ur'|uz'|uw0] + bias
    fgemm_k<2, false><<<dim3(32, 2), 512, 0, stream>>>(s_bf, nullptr, P1w,
                                                       nullptr, pre1,
                                                       bias_full, nullptr, nullptr);
    ec_k<<<dim3(2, 128), 512, 0, stream>>>(U8, x8, pre1, va, cpart, psum);
    gates_k<<<dim3(24, 2), 512, 0, stream>>>(cpart, psum, P2w, pre1, s_prev,
                                             rsb, zbuf, cu0);
    fgemm_k<4, false><<<dim3(8, 2), 512, 0, stream>>>(rsb, nullptr, P3w,
                                                      s_bf, s_cur,
                                                      cu0, zbuf, s_prev);
  }
  dout_k<<<256, 512, 0, stream>>>(s_hist, fcwT, fcb, dout);
}

// Round 15
// 740.158 us; speedup vs baseline: 1.0792x; 1.0595x over previous
//
#include <hip/hip_runtime.h>

#define NSTEP 16

typedef __attribute__((ext_vector_type(8))) short s16x8;
typedef __attribute__((ext_vector_type(4))) float f32x4;
typedef __attribute__((ext_vector_type(2))) float f32x2;

__device__ __forceinline__ float bf2f(unsigned short u){
  union { unsigned int i; float f; } v; v.i = ((unsigned int)u) << 16; return v.f;
}
__device__ __forceinline__ unsigned short f2bf(float f){
  union { float f; unsigned int i; } v; v.f = f;
  unsigned int r = v.i + 0x7fffu + ((v.i >> 16) & 1u);
  return (unsigned short)(r >> 16);
}
__device__ __forceinline__ float fast_rcp(float x){ return __builtin_amdgcn_rcpf(x); }
__device__ __forceinline__ float fast_tanh(float x){
  float e = __expf(2.0f * x);
  return 1.0f - 2.0f * fast_rcp(e + 1.0f);
}
__device__ __forceinline__ float fast_sigmoid(float x){
  return fast_rcp(1.0f + __expf(-x));
}
__device__ __forceinline__ void gload16(const void* g, void* l){
  __builtin_amdgcn_global_load_lds((const __attribute__((address_space(1))) void*)g,
                                   (__attribute__((address_space(3))) void*)l, 16, 0, 0);
}
__device__ __forceinline__ float wave_sum(float v){
#pragma unroll
  for (int off = 32; off; off >>= 1) v += __shfl_xor(v, off, 64);
  return v;
}
__device__ __forceinline__ void fp8x8_dec(uint2 w, float* u){
  f32x2 d0 = __builtin_amdgcn_cvt_pk_f32_fp8(w.x, false);
  f32x2 d1 = __builtin_amdgcn_cvt_pk_f32_fp8(w.x, true);
  f32x2 d2 = __builtin_amdgcn_cvt_pk_f32_fp8(w.y, false);
  f32x2 d3 = __builtin_amdgcn_cvt_pk_f32_fp8(w.y, true);
  u[0] = d0[0]; u[1] = d0[1]; u[2] = d1[0]; u[3] = d1[1];
  u[4] = d2[0]; u[5] = d2[1]; u[6] = d3[0]; u[7] = d3[1];
}
__device__ __forceinline__ s16x8 f32x8_to_bf8(float4 a, float4 b){
  s16x8 t8;
  t8[0] = (short)f2bf(a.x); t8[1] = (short)f2bf(a.y);
  t8[2] = (short)f2bf(a.z); t8[3] = (short)f2bf(a.w);
  t8[4] = (short)f2bf(b.x); t8[5] = (short)f2bf(b.y);
  t8[6] = (short)f2bf(b.z); t8[7] = (short)f2bf(b.w);
  return t8;
}
__device__ __forceinline__ uint2 f32x8_to_fp8(float4 a, float4 b){
  unsigned int lo, hi;
  lo = __builtin_amdgcn_cvt_pk_fp8_f32(a.x, a.y, 0, false);
  lo = __builtin_amdgcn_cvt_pk_fp8_f32(a.z, a.w, lo, true);
  hi = __builtin_amdgcn_cvt_pk_fp8_f32(b.x, b.y, 0, false);
  hi = __builtin_amdgcn_cvt_pk_fp8_f32(b.z, b.w, hi, true);
  uint2 w; w.x = lo; w.y = hi;
  return w;
}
__device__ __forceinline__ unsigned char f2fp8(float f){
  return (unsigned char)(__builtin_amdgcn_cvt_pk_fp8_f32(f, f, 0, false) & 0xff);
}

// ===== castx_k: x f32 -> x8 (fp8), pure stream =====
__global__ __launch_bounds__(256) void castx_k(const float* __restrict__ x,
                                               unsigned char* __restrict__ x8){
  size_t idx = (size_t)blockIdx.x * 256 + threadIdx.x;
  const float* p = x + idx * 8;
  float4 a = *(const float4*)p, b = *(const float4*)(p + 4);
  *(uint2*)(x8 + idx * 8) = f32x8_to_fp8(a, b);
}

// ===== ugemm8_k: U8 = fp8( (x8 @ Pua8) * 0.125 ), fp8 MFMA =====
// 128x128 tile, BK=64, grid (4, 512). LDS 16 KB. Pua8 holds fp8(8*ua^T).
struct G8LDS { unsigned char A[128 * 64]; unsigned char B[128 * 64]; };

__global__ __launch_bounds__(512) void ugemm8_k(
    const unsigned char* __restrict__ x8, const unsigned char* __restrict__ Pua8,
    unsigned char* __restrict__ U8){
  __shared__ G8LDS lds;
  const int tid = threadIdx.x;
  const int lane = tid & 63, wid = tid >> 6;
  const int wr = wid >> 2, wc = wid & 3;     // 2 x 4 waves, wave tile 64x32
  const int mt = blockIdx.y, nt = blockIdx.x;
  f32x4 acc[4][2];
#pragma unroll
  for (int m = 0; m < 4; ++m)
#pragma unroll
    for (int n = 0; n < 2; ++n) acc[m][n] = (f32x4)0.0f;

  const int row = tid >> 2, j = tid & 3;
  const int sc16 = j ^ (row & 3);
  for (int kt = 0; kt < 512; kt += 64){
    __syncthreads();
    gload16(x8  + (size_t)(mt * 128 + row) * 512 + kt + sc16 * 16, &lds.A[tid * 16]);
    gload16(Pua8 + (size_t)(nt * 128 + row) * 512 + kt + sc16 * 16, &lds.B[tid * 16]);
    __syncthreads();
#pragma unroll
    for (int ks = 0; ks < 2; ++ks){
      int g = (lane >> 4) + ks * 4;
      long av[4], bv[2];
#pragma unroll
      for (int m = 0; m < 4; ++m){
        int r = wr * 64 + m * 16 + (lane & 15);
        av[m] = *(const long*)&lds.A[r * 64 + ((g ^ ((r & 3) << 1)) << 3)];
      }
#pragma unroll
      for (int n = 0; n < 2; ++n){
        int c = wc * 32 + n * 16 + (lane & 15);
        bv[n] = *(const long*)&lds.B[c * 64 + ((g ^ ((c & 3) << 1)) << 3)];
      }
#pragma unroll
      for (int m = 0; m < 4; ++m)
#pragma unroll
        for (int n = 0; n < 2; ++n)
          acc[m][n] = __builtin_amdgcn_mfma_f32_16x16x32_fp8_fp8(av[m], bv[n], acc[m][n], 0, 0, 0);
    }
  }
#pragma unroll
  for (int m = 0; m < 4; ++m)
#pragma unroll
    for (int n = 0; n < 2; ++n){
      int r_base = mt * 128 + wr * 64 + m * 16 + ((lane >> 4) << 2);
      int col = nt * 128 + wc * 32 + n * 16 + (lane & 15);
#pragma unroll
      for (int q = 0; q < 4; ++q)
        U8[(size_t)(r_base + q) * 512 + col] = f2fp8(acc[m][n][q] * 0.125f);
    }
}

// ================= fast small GEMM: 64x64 tile, BK=256, 2 rounds =================
// EPI: 1 = s0 (tanh -> s_hist0 + s_bf; A from f32); 2 = pre1 (+bias, stride 2048);
//      4 = state update
struct FLDS { unsigned short A[64 * 256]; unsigned short B[64 * 256]; };  // 64 KB

template<int EPI, bool AF32>
__device__ __forceinline__ void fgemm_body(int mt, int nt,
    const unsigned short* __restrict__ A, const float* __restrict__ Af,
    const unsigned short* __restrict__ Bt,
    unsigned short* __restrict__ ob0, float* __restrict__ o0,
    const float* __restrict__ e0, const float* __restrict__ e1,
    const float* __restrict__ e2, FLDS& lds){
  const int tid = threadIdx.x;
  const int lane = tid & 63, wid = tid >> 6;
  const int wr = wid >> 1, wc = wid & 1;
  f32x4 acc[2];
  acc[0] = (f32x4)0.0f; acc[1] = (f32x4)0.0f;

  for (int kt = 0; kt < 512; kt += 256){
    if (kt) __syncthreads();
#pragma unroll
    for (int i = 0; i < 4; ++i){
      int s = i * 512 + tid;
      int row = s >> 5, c = s & 31;
      int sc = (c & 24) | ((c & 7) ^ (row & 7));
      if constexpr (AF32){
        const float* ap = Af + (size_t)(mt * 64 + row) * 512 + kt + sc * 8;
        float4 a0 = *(const float4*)ap, a1 = *(const float4*)(ap + 4);
        *(s16x8*)&lds.A[s * 8] = f32x8_to_bf8(a0, a1);
      } else {
        gload16(A + (size_t)(mt * 64 + row) * 512 + kt + sc * 8, &lds.A[s * 8]);
      }
      gload16(Bt + (size_t)(nt * 64 + row) * 512 + kt + sc * 8, &lds.B[s * 8]);
    }
    __syncthreads();
#pragma unroll
    for (int kk = 0; kk < 8; ++kk){
      int kch = kk * 4 + (lane >> 4);
      int ar = wr * 16 + (lane & 15);
      int asw = (kch & 24) | ((kch & 7) ^ (ar & 7));
      s16x8 av = *(const s16x8*)&lds.A[ar * 256 + asw * 8];
#pragma unroll
      for (int n = 0; n < 2; ++n){
        int br = wc * 32 + n * 16 + (lane & 15);
        int bsw = (kch & 24) | ((kch & 7) ^ (br & 7));
        s16x8 bv = *(const s16x8*)&lds.B[br * 256 + bsw * 8];
        acc[n] = __builtin_amdgcn_mfma_f32_16x16x32_bf16(av, bv, acc[n], 0, 0, 0);
      }
    }
  }

#pragma unroll
  for (int n = 0; n < 2; ++n){
    int r_base = mt * 64 + wr * 16 + ((lane >> 4) << 2);
    int col = nt * 64 + wc * 32 + n * 16 + (lane & 15);
#pragma unroll
    for (int q = 0; q < 4; ++q){
      float v = acc[n][q];
      size_t r_ = (size_t)(r_base + q);
      if constexpr (EPI == 1){
        float t = fast_tanh(v);
        o0[r_ * 512 + col] = t;
        ob0[r_ * 512 + col] = f2bf(t);
      } else if constexpr (EPI == 2){
        o0[r_ * 2048 + col] = v + e0[col];        // + bias_full
      } else if constexpr (EPI == 4){
        float v2 = v + e0[r_ * 512 + col];        // + cu0
        float sh = fast_tanh(v2);
        float z  = e1[r_ * 512 + col];            // z
        float so = e2[r_ * 512 + col];            // s_prev
        float sn = (1.0f - z) * so + z * sh;
        o0[r_ * 512 + col] = sn;                  // s_hist[step]
        ob0[r_ * 512 + col] = f2bf(sn);
      }
    }
  }
}

template<int EPI, bool AF32>
__global__ __launch_bounds__(512) void fgemm_k(
    const unsigned short* __restrict__ A, const float* __restrict__ Af,
    const unsigned short* __restrict__ Bt,
    unsigned short* __restrict__ ob0, float* __restrict__ o0,
    const float* __restrict__ e0, const float* __restrict__ e1,
    const float* __restrict__ e2){
  __shared__ FLDS lds;
  fgemm_body<EPI, AF32>(blockIdx.y, blockIdx.x, A, Af, Bt, ob0, o0, e0, e1, e2, lds);
}

// ec_k: grid (chunk=4, b=128), 512 thr (8 waves x 16 t each) -> 2 blocks/CU
__global__ __launch_bounds__(512) void ec_k(const unsigned char* __restrict__ U8,
    const unsigned char* __restrict__ x8, const float* __restrict__ pre1,
    const float* __restrict__ va, float* __restrict__ cpart, float* __restrict__ psum){
  __shared__ float cred[8][512];
  __shared__ float pred[8];
  int chunk = blockIdx.x, b = blockIdx.y;
  int tid = threadIdx.x, lane = tid & 63, wid = tid >> 6;
  const float* pp = pre1 + (size_t)b * 2048 + lane * 8;
  float4 p0 = *(const float4*)pp, p1 = *(const float4*)(pp + 4);
  const float* vp = va + lane * 8;
  float4 v0 = *(const float4*)vp, v1 = *(const float4*)(vp + 4);
  float sv[8] = {p0.x, p0.y, p0.z, p0.w, p1.x, p1.y, p1.z, p1.w};
  float vv[8] = {v0.x, v0.y, v0.z, v0.w, v1.x, v1.y, v1.z, v1.w};
  float acc[8] = {0, 0, 0, 0, 0, 0, 0, 0};
  float psum_l = 0.f;
  int t0 = chunk * 128 + wid * 16;
  for (int i = 0; i < 16; ++i){
    int t = t0 + i;
    uint2 w = *(const uint2*)(U8 + ((size_t)t * 128 + b) * 512 + lane * 8);
    float u[8];
    fp8x8_dec(w, u);
    float e = 0.f;
#pragma unroll
    for (int k = 0; k < 8; ++k)
      e += fast_tanh(u[k] + sv[k]) * vv[k];
    e = wave_sum(e);
    float p = __expf(e);
    psum_l += p;
    uint2 wx = *(const uint2*)(x8 + ((size_t)t * 128 + b) * 512 + lane * 8);
    float ux[8];
    fp8x8_dec(wx, ux);
#pragma unroll
    for (int k = 0; k < 8; ++k) acc[k] += p * ux[k];
  }
#pragma unroll
  for (int k = 0; k < 8; ++k) cred[wid][lane * 8 + k] = acc[k];
  if (lane == 0) pred[wid] = psum_l;
  __syncthreads();
  float cs = 0.f;
#pragma unroll
  for (int w = 0; w < 8; ++w) cs += cred[w][tid];
  cpart[((size_t)chunk * 128 + b) * 512 + tid] = cs;
  if (tid == 0){
    float s = 0.f;
#pragma unroll
    for (int w = 0; w < 8; ++w) s += pred[w];
    psum[chunk * 128 + b] = s;
  }
}

// gates_k: 64x64 tiles (grid 24 x 2), A = c (4 partials, normalized)
__global__ __launch_bounds__(512) void gates_k(
    const float* __restrict__ cpart, const float* __restrict__ psum,
    const unsigned short* __restrict__ P2w, const float* __restrict__ pre1,
    const float* __restrict__ s_prev,
    unsigned short* __restrict__ rsb, float* __restrict__ zbuf, float* __restrict__ cu0){
  __shared__ FLDS lds;
  __shared__ float rden_s[64];
  const int tid = threadIdx.x;
  const int lane = tid & 63, wid = tid >> 6;
  const int wr = wid >> 1, wc = wid & 1;
  const int nt = blockIdx.x, mt = blockIdx.y;
  if (tid < 64){
    float d = 0.f;
#pragma unroll
    for (int ch = 0; ch < 4; ++ch) d += psum[ch * 128 + mt * 64 + tid];
    rden_s[tid] = fast_rcp(d);
  }
  f32x4 acc[2];
  acc[0] = (f32x4)0.0f; acc[1] = (f32x4)0.0f;

  for (int kt = 0; kt < 512; kt += 256){
    __syncthreads();
#pragma unroll
    for (int i = 0; i < 4; ++i){
      int s = i * 512 + tid;
      int row = s >> 5, c = s & 31;
      int sc = (c & 24) | ((c & 7) ^ (row & 7));
      int b = mt * 64 + row;
      float rd = rden_s[row];
      float vsum[8] = {0, 0, 0, 0, 0, 0, 0, 0};
#pragma unroll
      for (int ch = 0; ch < 4; ++ch){
        const float* cp = cpart + ((size_t)ch * 128 + b) * 512 + kt + sc * 8;
        float4 a0 = *(const float4*)cp, a1 = *(const float4*)(cp + 4);
        vsum[0] += a0.x; vsum[1] += a0.y; vsum[2] += a0.z; vsum[3] += a0.w;
        vsum[4] += a1.x; vsum[5] += a1.y; vsum[6] += a1.z; vsum[7] += a1.w;
      }
      s16x8 t8;
#pragma unroll
      for (int k = 0; k < 8; ++k) t8[k] = (short)f2bf(vsum[k] * rd);
      *(s16x8*)&lds.A[s * 8] = t8;
      gload16(P2w + (size_t)(nt * 64 + row) * 512 + kt + sc * 8, &lds.B[s * 8]);
    }
    __syncthreads();
#pragma unroll
    for (int kk = 0; kk < 8; ++kk){
      int kch = kk * 4 + (lane >> 4);
      int ar = wr * 16 + (lane & 15);
      int asw = (kch & 24) | ((kch & 7) ^ (ar & 7));
      s16x8 av = *(const s16x8*)&lds.A[ar * 256 + asw * 8];
#pragma unroll
      for (int n = 0; n < 2; ++n){
        int br = wc * 32 + n * 16 + (lane & 15);
        int bsw = (kch & 24) | ((kch & 7) ^ (br & 7));
        s16x8 bv = *(const s16x8*)&lds.B[br * 256 + bsw * 8];
        acc[n] = __builtin_amdgcn_mfma_f32_16x16x32_bf16(av, bv, acc[n], 0, 0, 0);
      }
    }
  }

#pragma unroll
  for (int n = 0; n < 2; ++n){
    int r_base = mt * 64 + wr * 16 + ((lane >> 4) << 2);
    int col = nt * 64 + wc * 32 + n * 16 + (lane & 15);
#pragma unroll
    for (int q = 0; q < 4; ++q){
      float v = acc[n][q];
      size_t r_ = (size_t)(r_base + q);
      float v2 = v + pre1[r_ * 2048 + 512 + col];
      if (col < 512){
        float rg = fast_sigmoid(v2);
        rsb[r_ * 512 + col] = f2bf(rg * s_prev[r_ * 512 + col]);
      } else if (col < 1024){
        zbuf[r_ * 512 + (col - 512)] = fast_sigmoid(v2);
      } else {
        cu0[r_ * 512 + (col - 1024)] = v2;
      }
    }
  }
}

// dout_k: all outputs from s_hist in one pass
__global__ __launch_bounds__(512) void dout_k(const float* __restrict__ s_hist,
    const float* __restrict__ fcwT, const float* __restrict__ fcb,
    float* __restrict__ dout){
  int lane = threadIdx.x & 63, wid = threadIdx.x >> 6;
  int w = blockIdx.x * 8 + wid;            // 0..2047
  int step = w >> 7, b = w & 127;
  const float* sp = s_hist + (size_t)w * 512 + lane * 8;
  float4 sa = *(const float4*)sp, sb = *(const float4*)(sp + 4);
#pragma unroll
  for (int o = 0; o < 12; ++o){
    const float* fp = fcwT + (size_t)o * 512 + lane * 8;
    float4 fa = *(const float4*)fp, fb = *(const float4*)(fp + 4);
    float sum = sa.x * fa.x + sa.y * fa.y + sa.z * fa.z + sa.w * fa.w +
                sb.x * fb.x + sb.y * fb.y + sb.z * fb.z + sb.w * fb.w;
    sum = wave_sum(sum);
    if (lane == 0)
      dout[(size_t)b * (NSTEP * 12) + step * 12 + o] = sum + fcb[o];
  }
}

// weight prep: transposed matrices (ua -> fp8x8 Pua8; rest bf16, with
// out-folding), fcwT, bias_full
__global__ __launch_bounds__(512) void trans_k(
    const float* __restrict__ ua, const float* __restrict__ wsm,
    const float* __restrict__ u0, const float* __restrict__ wa,
    const float* __restrict__ urm, const float* __restrict__ uz,
    const float* __restrict__ cr, const float* __restrict__ cz,
    const float* __restrict__ c0, const float* __restrict__ wrm,
    const float* __restrict__ wzm, const float* __restrict__ w0m,
    const float* __restrict__ fcw, const float* __restrict__ fcb,
    unsigned char* __restrict__ Pua8, unsigned short* __restrict__ Pws,
    unsigned short* __restrict__ P3w, unsigned short* __restrict__ P1w,
    unsigned short* __restrict__ P2w, float* __restrict__ fcwT,
    float* __restrict__ bias_full){
  __shared__ unsigned short tr[64][72];
  int bid = blockIdx.x, tid = threadIdx.x;
  if (bid < 640){
    int mi = bid >> 6, tile = bid & 63;
    int trr = tile >> 3, tcc = tile & 7;
    const float* src = nullptr; const float* W = nullptr; unsigned short* dst = nullptr;
    switch (mi){
      case 0: src = ua;  dst = nullptr;           break;   // -> Pua8 (fp8)
      case 1: src = wsm; dst = Pws;               break;
      case 2: src = u0;  dst = P3w;               break;
      case 3: src = wa;  dst = P1w;               break;
      case 4: src = urm; dst = P1w + 512 * 512;  W = wrm; break;
      case 5: src = uz;  dst = P1w + 1024 * 512; W = wzm; break;
      case 6: src = nullptr; dst = P1w + 1536 * 512; W = w0m; break;
      case 7: src = cr;  dst = P2w;               break;
      case 8: src = cz;  dst = P2w + 512 * 512;   break;
      default:src = c0;  dst = P2w + 1024 * 512;  break;
    }
    int r = tid >> 3, c8 = (tid & 7) * 8;
    int h = trr * 64 + r;
    float vals[8];
    if (src){
      const float* sp = src + (size_t)h * 512 + tcc * 64 + c8;
      float4 a = *(const float4*)sp, b = *(const float4*)(sp + 4);
      vals[0] = a.x; vals[1] = a.y; vals[2] = a.z; vals[3] = a.w;
      vals[4] = b.x; vals[5] = b.y; vals[6] = b.z; vals[7] = b.w;
    } else {
#pragma unroll
      for (int k = 0; k < 8; ++k) vals[k] = 0.f;
    }
    if (W){
      float fr[12];
#pragma unroll
      for (int o = 0; o < 12; ++o) fr[o] = fcw[h * 12 + o];
#pragma unroll
      for (int jj = 0; jj < 8; ++jj){
        int j = tcc * 64 + c8 + jj;
        float cj = 0.f;
#pragma unroll
        for (int o = 0; o < 12; ++o) cj += fr[o] * W[o * 512 + j];
        vals[jj] += cj;
      }
    }
    unsigned short* lp = &tr[r][c8];
#pragma unroll
    for (int k = 0; k < 8; ++k) lp[k] = f2bf(vals[k]);
    __syncthreads();
    if (mi == 0){
      float v[8];
#pragma unroll
      for (int k = 0; k < 8; ++k) v[k] = bf2f(tr[c8 + k][r]) * 8.0f;
      float4 a; a.x = v[0]; a.y = v[1]; a.z = v[2]; a.w = v[3];
      float4 b; b.x = v[4]; b.y = v[5]; b.z = v[6]; b.w = v[7];
      *(uint2*)(Pua8 + (size_t)(tcc * 64 + r) * 512 + trr * 64 + c8) = f32x8_to_fp8(a, b);
    } else {
      s16x8 o8v;
#pragma unroll
      for (int k = 0; k < 8; ++k) o8v[k] = (short)tr[c8 + k][r];
      *(s16x8*)(dst + (size_t)(tcc * 64 + r) * 512 + trr * 64 + c8) = o8v;
    }
  } else if (bid < 652){
    int gidx = (bid - 640) * 512 + tid;   // 0..6143
    int h = gidx / 12, o = gidx - h * 12;
    fcwT[(size_t)o * 512 + h] = fcw[h * 12 + o];
  } else {
#pragma unroll
    for (int p = 0; p < 4; ++p){
      int col = p * 512 + tid;
      float v = 0.f;
      if (p > 0){
        const float* W = (p == 1) ? wrm : (p == 2) ? wzm : w0m;
#pragma unroll
        for (int o = 0; o < 12; ++o) v += fcb[o] * W[o * 512 + tid];
      }
      bias_full[col] = v;
    }
  }
}

// ---------------- host launch ----------------
extern "C" void kernel_launch(void* const* d_in, const int* in_sizes, int n_in,
                              void* d_out, int out_size, void* d_ws, size_t ws_size,
                              hipStream_t stream){
  const float* x   = (const float*)d_in[0];
  const float* w0  = (const float*)d_in[1];
  const float* wz  = (const float*)d_in[2];
  const float* wrm = (const float*)d_in[3];
  const float* wsm = (const float*)d_in[4];
  const float* wa  = (const float*)d_in[5];
  const float* ua  = (const float*)d_in[6];
  const float* va  = (const float*)d_in[7];
  const float* u0  = (const float*)d_in[8];
  const float* uz  = (const float*)d_in[9];
  const float* urm = (const float*)d_in[10];
  const float* c0  = (const float*)d_in[11];
  const float* cz  = (const float*)d_in[12];
  const float* cr  = (const float*)d_in[13];
  const float* fcw = (const float*)d_in[14];
  const float* fcb = (const float*)d_in[15];
  float* dout = (float*)d_out;

  char* base = (char*)d_ws;
  size_t off = 0;
  auto alloc = [&](size_t bytes) -> char* {
    char* p = base + off; off += (bytes + 255) & ~(size_t)255; return p;
  };
  unsigned char*  x8   = (unsigned char*) alloc((size_t)512 * 128 * 512);
  unsigned char*  U8   = (unsigned char*) alloc((size_t)512 * 128 * 512);
  unsigned char*  Pua8 = (unsigned char*) alloc(512 * 512);
  unsigned short* Pws  = (unsigned short*)alloc(512 * 512 * 2);
  unsigned short* P3w  = (unsigned short*)alloc(512 * 512 * 2);
  unsigned short* P1w  = (unsigned short*)alloc((size_t)2048 * 512 * 2);
  unsigned short* P2w  = (unsigned short*)alloc((size_t)1536 * 512 * 2);
  float* fcwT          = (float*)alloc(12 * 512 * 4);
  float* bias_full     = (float*)alloc(2048 * 4);
  float* pre1          = (float*)alloc((size_t)128 * 2048 * 4);
  float* cpart         = (float*)alloc((size_t)4 * 128 * 512 * 4);
  float* psum          = (float*)alloc(4 * 128 * 4);
  unsigned short* rsb  = (unsigned short*)alloc((size_t)128 * 512 * 2);
  float* zbuf          = (float*)alloc((size_t)128 * 512 * 4);
  float* cu0           = (float*)alloc((size_t)128 * 512 * 4);
  float* s_hist        = (float*)alloc((size_t)NSTEP * 128 * 512 * 4);
  unsigned short* s_bf = (unsigned short*)alloc((size_t)128 * 512 * 2);
  (void)ws_size; (void)in_sizes; (void)n_in; (void)out_size;

  // setup
  trans_k<<<653, 512, 0, stream>>>(ua, wsm, u0, wa, urm, uz, cr, cz, c0,
                                   wrm, wz, w0, fcw, fcb,
                                   Pua8, Pws, P3w, P1w, P2w, fcwT, bias_full);
  castx_k<<<16384, 256, 0, stream>>>(x, x8);
  // U8 = fp8( (x8 @ fp8(8*ua)) / 8 )
  ugemm8_k<<<dim3(4, 512), 512, 0, stream>>>(x8, Pua8, U8);
  // s0 = tanh(x0 @ ws) -> s_hist[0] + s_bf  (A from f32 x rows 0..127)
  fgemm_k<1, true><<<dim3(8, 2), 512, 0, stream>>>(nullptr, x, Pws, s_bf, s_hist,
                                                   nullptr, nullptr, nullptr);

  for (int step = 1; step < NSTEP; ++step){
    const float* s_prev = s_hist + (size_t)(step - 1) * 128 * 512;
    float* s_cur = s_hist + (size_t)step * 128 * 512;
    // pre1 = s @ [wa|ur'|uz'|uw0] + bias
    fgemm_k<2, false><<<dim3(32, 2), 512, 0, stream>>>(s_bf, nullptr, P1w,
                                                       nullptr, pre1,
                                                       bias_full, nullptr, nullptr);
    ec_k<<<dim3(4, 128), 512, 0, stream>>>(U8, x8, pre1, va, cpart, psum);
    gates_k<<<dim3(24, 2), 512, 0, stream>>>(cpart, psum, P2w, pre1, s_prev,
                                             rsb, zbuf, cu0);
    fgemm_k<4, false><<<dim3(8, 2), 512, 0, stream>>>(rsb, nullptr, P3w,
                                                      s_bf, s_cur,
                                                      cu0, zbuf, s_prev);
  }
  dout_k<<<256, 512, 0, stream>>>(s_hist, fcwT, fcb, dout);
}